// Round 7
// baseline (160.249 us; speedup 1.0000x reference)
//
#include <hip/hip_runtime.h>

// Varifold loss, round 19: rotated (wait-free) iteration at CONSTANT 64-AGPR
// peak. Round-12/18 body stalls ~MFMA-latency between issuing its 4 MFMAs
// and the first dependent exp2, and all co-resident waves replicate the
// stall in phase (VALUBusy pinned ~72% across occupancies/staggers/trims).
// Rotation: carry tile-0's accumulator across the iteration boundary:
//   body(k): issue B=mfma(tile1,b_k); prefetch b_{k+1}; EPI(A carried);
//            A=mfma(tile0,b_{k+1}); EPI(B)
// Every EPI consumes an MFMA issued >=170 cy earlier -> no wait window,
// regardless of wave phasing. Peak acc liveness stays 64 regs (A dies in
// EPI before A' is created). Both epilogues of chunk k remain inside
// iteration k -> round-18 sign-flip/diagonal logic unchanged. Last
// iteration's trailing A-issue reads the 27-chunk pad (never consumed).
//
// t_ij = cq_i + cq_j + TG*<C_i,C_j>;  d_ij = <m_i,m_j>;  term = exp2(t)*d^2.
// A-op K=16: [TGh(3),TGl(3),TGh(3),TGl(3),cqh,cql,1,1]
// B-op K=16: [Ch(3),Ch(3),Cl(3),Cl(3),1,1,cqh,cql]
// d:  A=[mh,ml,mh,ml,0^4], B=[mh,mh,ml,ml,0^4]   (exact hi/lo split)

#define NVERT 5023
#define NFACE 9976
#define BATCH 4
#define HALFP 9984             // per-mesh faces padded: 39 panels x 256
#define NTP   (2 * HALFP)      // 19968 faces per batch
#define NTOT  (BATCH * NTP)    // 79872
#define NCH   624              // j-chunks of 32 per batch
#define NPAN  78               // i-panels of 256
#define SPLITS 26
#define BPAD  (27 * 32)        // prefetch over-read pad (records)

constexpr float GAMMA = 1.0f / (0.03f * 0.03f);
constexpr float LOG2E = 1.4426950408889634f;
constexpr float EPSV  = 1e-12f;

typedef _Float16 half8_t  __attribute__((ext_vector_type(8)));
typedef float    f32x16   __attribute__((ext_vector_type(16)));
typedef float    f32x2    __attribute__((ext_vector_type(2)));

__global__ __launch_bounds__(256)
void face_quant_kernel(const float* __restrict__ pred,
                       const float* __restrict__ targ,
                       const int*   __restrict__ faces,
                       _Float16*    __restrict__ fd,
                       float*       __restrict__ out) {
    int idx = blockIdx.x * 256 + threadIdx.x;
    if (idx == 0) out[0] = 0.0f;
    if (idx >= NTOT) return;

    int b     = idx / NTP;
    int s     = idx - b * NTP;
    int which = (s >= HALFP) ? 1 : 0;
    int f     = s - which * HALFP;

    _Float16* arec = fd + (size_t)idx * 32;
    _Float16* brec = fd + (size_t)NTOT * 32 + (size_t)idx * 32;

    if (f >= NFACE) {
        half8_t z = {};
        *(half8_t*)(arec + 0) = z; *(half8_t*)(arec + 8)  = z;
        *(half8_t*)(arec + 16) = z; *(half8_t*)(arec + 24) = z;
        *(half8_t*)(brec + 0) = z; *(half8_t*)(brec + 8)  = z;
        *(half8_t*)(brec + 16) = z; *(half8_t*)(brec + 24) = z;
        return;
    }

    const float* V = (which ? targ : pred) + (size_t)b * NVERT * 3;
    int i0 = faces[f * 3 + 0];
    int i1 = faces[f * 3 + 1];
    int i2 = faces[f * 3 + 2];

    float v0x = V[i0*3+0], v0y = V[i0*3+1], v0z = V[i0*3+2];
    float v1x = V[i1*3+0], v1y = V[i1*3+1], v1z = V[i1*3+2];
    float v2x = V[i2*3+0], v2y = V[i2*3+1], v2z = V[i2*3+2];

    const float third = 1.0f / 3.0f;
    float cx = (v0x + v1x + v2x) * third;
    float cy = (v0y + v1y + v2y) * third;
    float cz = (v0z + v1z + v2z) * third;

    float e1x = v1x - v0x, e1y = v1y - v0y, e1z = v1z - v0z;
    float e2x = v2x - v0x, e2y = v2y - v0y, e2z = v2z - v0z;

    float nx = 0.5f * (e1y * e2z - e1z * e2y);
    float ny = 0.5f * (e1z * e2x - e1x * e2z);
    float nz = 0.5f * (e1x * e2y - e1y * e2x);

    float L   = sqrtf(nx*nx + ny*ny + nz*nz);
    float inv = 1.0f / fmaxf(L, EPSV);
    float sc  = inv * sqrtf(L);            // m = Nn*sqrt(L)
    float mx = nx * sc, my = ny * sc, mz = nz * sc;

    const float TG = 2.0f * GAMMA * LOG2E;
    float tgx = TG * cx, tgy = TG * cy, tgz = TG * cz;
    float cq  = -GAMMA * LOG2E * (cx*cx + cy*cy + cz*cz);

    _Float16 TGxh = (_Float16)tgx; _Float16 TGxl = (_Float16)(tgx - (float)TGxh);
    _Float16 TGyh = (_Float16)tgy; _Float16 TGyl = (_Float16)(tgy - (float)TGyh);
    _Float16 TGzh = (_Float16)tgz; _Float16 TGzl = (_Float16)(tgz - (float)TGzh);
    _Float16 Cxh  = (_Float16)cx;  _Float16 Cxl  = (_Float16)(cx  - (float)Cxh);
    _Float16 Cyh  = (_Float16)cy;  _Float16 Cyl  = (_Float16)(cy  - (float)Cyh);
    _Float16 Czh  = (_Float16)cz;  _Float16 Czl  = (_Float16)(cz  - (float)Czh);
    _Float16 cqh  = (_Float16)cq;  _Float16 cql  = (_Float16)(cq  - (float)cqh);
    _Float16 mxh  = (_Float16)mx;  _Float16 mxl  = (_Float16)(mx  - (float)mxh);
    _Float16 myh  = (_Float16)my;  _Float16 myl  = (_Float16)(my  - (float)myh);
    _Float16 mzh  = (_Float16)mz;  _Float16 mzl  = (_Float16)(mz  - (float)mzh);
    _Float16 one  = (_Float16)1.0f;
    _Float16 zz   = (_Float16)0.0f;

    half8_t ta0 = {TGxh, TGyh, TGzh, TGxl, TGyl, TGzl, TGxh, TGyh};
    half8_t ta1 = {TGzh, TGxl, TGyl, TGzl, cqh,  cql,  one,  one };
    half8_t da0 = {mxh,  myh,  mzh,  mxl,  myl,  mzl,  mxh,  myh };
    half8_t da1 = {mzh,  mxl,  myl,  mzl,  zz,   zz,   zz,   zz  };
    half8_t tb0 = {Cxh,  Cyh,  Czh,  Cxh,  Cyh,  Czh,  Cxl,  Cyl };
    half8_t tb1 = {Czl,  Cxl,  Cyl,  Czl,  one,  one,  cqh,  cql };
    half8_t db0 = {mxh,  myh,  mzh,  mxh,  myh,  mzh,  mxl,  myl };
    half8_t db1 = {mzl,  mxl,  myl,  mzl,  zz,   zz,   zz,   zz  };

    *(half8_t*)(arec + 0)  = ta0;  *(half8_t*)(arec + 8)  = ta1;
    *(half8_t*)(arec + 16) = da0;  *(half8_t*)(arec + 24) = da1;
    *(half8_t*)(brec + 0)  = tb0;  *(half8_t*)(brec + 8)  = tb1;
    *(half8_t*)(brec + 16) = db0;  *(half8_t*)(brec + 24) = db1;
}

__device__ __forceinline__ half8_t ld8(const _Float16* p) {
    return *(const half8_t*)p;
}

// Packed epilogue of one accumulator pair into the 4 chains.
#define EPI(T_, D_)                                                          \
    {                                                                        \
        _Pragma("unroll")                                                    \
        for (int r = 0; r < 16; r += 2) {                                    \
            f32x2 e_ = {__builtin_amdgcn_exp2f((T_)[r]),                     \
                        __builtin_amdgcn_exp2f((T_)[r + 1])};                \
            f32x2 d_ = {(D_)[r], (D_)[r + 1]};                               \
            d_ = d_ * d_;                                                    \
            aa[(r >> 1) & 3] = e_ * d_ + aa[(r >> 1) & 3];                   \
        }                                                                    \
    }

// Rotated body for chunk K_: issue tile1 on the CURRENT b slot, prefetch
// the next chunk into the OTHER slot, drain the carried tile-0 accumulator
// (issued last iteration), re-issue tile-0 on the freshly loaded slot,
// drain tile1. Peak accumulator liveness: 64 regs (two f32x16 pairs).
#define RBODY(CT_, CD_, NT_, ND_, K_)                                        \
    {                                                                        \
        if ((K_) == ktrig) {                                                 \
            aa[0] = -aa[0]; aa[1] = -aa[1]; aa[2] = -aa[2]; aa[3] = -aa[3];  \
        }                                                                    \
        f32x16 Tb = __builtin_amdgcn_mfma_f32_32x32x16_f16(aT1, CT_, z, 0, 0, 0); \
        f32x16 Db = __builtin_amdgcn_mfma_f32_32x32x16_f16(aD1, CD_, z, 0, 0, 0); \
        pB += JSTEP;                                                         \
        NT_ = ld8(pB);                                                       \
        ND_ = ld8(pB + 16);                                                  \
        EPI(Ta, Da)                        /* tile0, chunk K_ (carried) */   \
        __builtin_amdgcn_sched_barrier(0);                                   \
        Ta = __builtin_amdgcn_mfma_f32_32x32x16_f16(aT0, NT_, z, 0, 0, 0);   \
        Da = __builtin_amdgcn_mfma_f32_32x32x16_f16(aD0, ND_, z, 0, 0, 0);   \
        EPI(Tb, Db)                        /* tile1, chunk K_ */             \
        if ((K_) == 0 && s < 8) {                                            \
            f32x2 C2 = (aa[0] + aa[1]) + (aa[2] + aa[3]);                    \
            acc = fmaf(-sign0, C2.x + C2.y, acc);                            \
        }                                                                    \
    }

__global__ __launch_bounds__(256, 4)
void pair_sum_kernel(const _Float16* __restrict__ fd,
                     float*          __restrict__ out) {
    const int b       = blockIdx.z;
    const int pairIdx = blockIdx.x / SPLITS;     // 0..38
    const int s       = blockIdx.x % SPLITS;

    const _Float16* Arec = fd;
    const _Float16* Brec = fd + (size_t)NTOT * 32;

    const int lane = threadIdx.x & 63;
    const int w    = threadIdx.x >> 6;
    const int col  = lane & 31;
    const int koff = (lane >> 5) * 8;

    const size_t bface = (size_t)b * NTP;
    const size_t JSTEP = (size_t)SPLITS * 32 * 32;

    float acc = 0.0f;
    const f32x16 z = {};

    #pragma unroll 1
    for (int h = 0; h < 2; ++h) {
        const int   P  = h ? (NPAN - 1 - pairIdx) : pairIdx;
        const int   c0 = 8 * P;
        const float si = (P < NPAN / 2) ? 1.0f : -1.0f;
        const int   iters = (NCH - c0 - s + SPLITS - 1) / SPLITS;
        if (iters <= 0) continue;

        // sign regions: chunks k < kcross have sign si, k >= kcross have -si
        const int   rem      = NCH / 2 - (c0 + s);
        const int   kcross   = (rem > 0) ? ((rem + SPLITS - 1) / SPLITS) : 0;
        const float sign0    = (kcross > 0) ? si : -si;
        const float signLast = (kcross >= iters) ? si : -si;
        const int   ktrig    = (kcross >= 1 && kcross < iters) ? kcross : -1;

        // two i-tiles per wave: rows P*256 + w*32 (+128)
        const _Float16* ap0 = Arec + (bface + (size_t)(P * 256 + w * 32 + col)) * 32 + koff;
        const _Float16* ap1 = ap0 + (size_t)128 * 32;
        half8_t aT0 = ld8(ap0);
        half8_t aD0 = ld8(ap0 + 16);
        half8_t aT1 = ld8(ap1);
        half8_t aD1 = ld8(ap1 + 16);

        const _Float16* pB =
            Brec + (bface + (size_t)((c0 + s) * 32 + col)) * 32 + koff;
        half8_t bTa = ld8(pB);
        half8_t bDa = ld8(pB + 16);
        half8_t bTb, bDb;

        f32x2 aa[4] = {};

        // prologue: issue tile0 of chunk 0 (carried into iteration 0)
        f32x16 Ta = __builtin_amdgcn_mfma_f32_32x32x16_f16(aT0, bTa, z, 0, 0, 0);
        f32x16 Da = __builtin_amdgcn_mfma_f32_32x32x16_f16(aD0, bDa, z, 0, 0, 0);

        // rotated main loop, 2x-unrolled ping-pong b slots
        int k = 0;
        for (;;) {
            RBODY(bTa, bDa, bTb, bDb, k)
            if (++k >= iters) break;
            RBODY(bTb, bDb, bTa, bDa, k)
            if (++k >= iters) break;
        }
        // trailing Ta/Da (chunk `iters`) read the pad and are never drained.

        f32x2 A2 = (aa[0] + aa[1]) + (aa[2] + aa[3]);
        acc = fmaf(2.0f * signLast, A2.x + A2.y, acc);
    }

    acc *= (1.0f / BATCH);

    #pragma unroll
    for (int off = 32; off > 0; off >>= 1)
        acc += __shfl_down(acc, off, 64);

    __shared__ float wsum[4];
    if (lane == 0) wsum[w] = acc;
    __syncthreads();
    if (threadIdx.x == 0)
        atomicAdd(out, wsum[0] + wsum[1] + wsum[2] + wsum[3]);
}

extern "C" void kernel_launch(void* const* d_in, const int* in_sizes, int n_in,
                              void* d_out, int out_size, void* d_ws, size_t ws_size,
                              hipStream_t stream) {
    const float* pred  = (const float*)d_in[0];
    const float* targ  = (const float*)d_in[1];
    const int*   faces = (const int*)d_in[2];
    float*       out   = (float*)d_out;
    _Float16*    fd    = (_Float16*)d_ws;
    // layout: A region NTOT*32 halfs | B region NTOT*32 halfs | BPAD*32 pad
    // = 10.22 MB + 54 KB (pad read-only, values discarded)

    face_quant_kernel<<<(NTOT + 255) / 256, 256, 0, stream>>>(
        pred, targ, faces, fd, out);

    dim3 grid((NPAN / 2) * SPLITS, 1, BATCH);   // 1014 x 1 x 4 = 4056 blocks
    pair_sum_kernel<<<grid, 256, 0, stream>>>(fd, out);
}